// Round 4
// baseline (182.564 us; speedup 1.0000x reference)
//
#include <hip/hip_runtime.h>

// ---------------------------------------------------------------------------
// out[b,i] = (x@L^T)[b,i] + quad_mean[b] + cubic_mean[b] + (i==0)*cT[b] + (i==1)*cH[b]
// quad_mean[b] = sum_h relu(x@qW1 + qb1)[b,h] * colmean(qW2)[h] + mean(qb2)
//
// Round 11: fuse nl_gemm + lin_gemm into ONE kernel via a software per-m-slab
// barrier (plain device-scope atomics; cooperative launch is dead on this
// harness, round-8 evidence). Residency for the spin is GUARANTEED:
// grid 512 blocks, __launch_bounds__(256,2) -> >=2 blocks/CU -> all 512
// co-resident. Block (m,g): nl tiles (m,2g),(m,2g+1) -> rowadd atomics ->
// cnt[m]++; then runs the lin k-loop WITHOUT waiting (sync hidden under
// ~8 K-steps of MFMA); spins on cnt[m]==4 only before the epilogue reads
// rowadd. lin re-reads the same A-slab the block just used (L2-hot).
// GEMM interior (BK=64, 128x128, 16x16x32 bf16, gload_lds 16B, XOR swizzle
// chunk(row,kc)->slot kc^(row&7)) is bit-identical to the verified kernel.
// ---------------------------------------------------------------------------

#define OMEGA_F 0.5235987755982988f

typedef __attribute__((ext_vector_type(8))) short short8;
typedef __attribute__((ext_vector_type(4))) float f32x4;

__device__ __forceinline__ unsigned short f2bf(float f) {
  union { float f; unsigned int u; } a;
  a.f = f;
  unsigned int u = a.u;
  return (unsigned short)((u + 0x7fffu + ((u >> 16) & 1u)) >> 16);
}

// async global -> LDS, 16 B per lane; LDS dst wave-uniform, lane i -> base+i*16
__device__ __forceinline__ void gload16(const void* g, void* l) {
  __builtin_amdgcn_global_load_lds(
      (const __attribute__((address_space(1))) unsigned int*)g,
      (__attribute__((address_space(3))) unsigned int*)l, 16, 0, 0);
}

// ---- k1: all prep work in one launch (one change: zero cnt[]) --------------
__global__ void prep_conv(const float* __restrict__ fc, const float* __restrict__ qW1,
                          const float* __restrict__ cW1, const float* __restrict__ t,
                          const float* __restrict__ qW2, const float* __restrict__ cW2,
                          const float* __restrict__ qb2, const float* __restrict__ cb2,
                          const float4* __restrict__ x4, const float* __restrict__ x,
                          const float* __restrict__ tW1, const float* __restrict__ tb1,
                          const float* __restrict__ tW2, const float* __restrict__ tb2,
                          const float* __restrict__ hW1, const float* __restrict__ hb1,
                          const float* __restrict__ hW2, const float* __restrict__ hb2,
                          unsigned short* __restrict__ WT, uint2* __restrict__ xb,
                          float* __restrict__ qw2m, float* __restrict__ cw2m,
                          float* __restrict__ b2m, float* __restrict__ cT,
                          float* __restrict__ cH, float* __restrict__ rowadd,
                          unsigned int* __restrict__ cnt) {
  int b = blockIdx.x, tdx = threadIdx.x;
  if (b < 3072) {
    // WcatT (1536 x 512 bf16, n-major): [ L | quad_W1^T | cubic_W1^T ]
    int idx = b * 256 + tdx;
    int n = idx >> 9;
    int k = idx & 511;
    float v;
    if (n < 512) {
      float th = OMEGA_F * t[0];
      float s1, c1, s2, c2;
      sincosf(th, &s1, &c1);
      sincosf(2.0f * th, &s2, &c2);
      const float* p = fc + ((size_t)n * 512 + k) * 5;
      v = p[0] + p[1] * c1 + p[2] * s1 + p[3] * c2 + p[4] * s2;
    } else if (n < 1024) {
      v = qW1[(size_t)k * 512 + (n - 512)];
    } else {
      v = cW1[(size_t)k * 512 + (n - 1024)];
    }
    WT[idx] = f2bf(v);
  } else if (b < 3076) {
    int bb = b - 3072;
    const float* W = (bb < 2) ? qW2 : cW2;
    float* o = (bb < 2) ? qw2m : cw2m;
    int h = (bb & 1) * 256 + tdx;
    const float4* row = (const float4*)(W + (size_t)h * 512);
    float s = 0.f;
    for (int i = 0; i < 128; ++i) { float4 v = row[i]; s += (v.x + v.y) + (v.z + v.w); }
    o[h] = s * (1.0f / 512.0f);
  } else if (b == 3076) {
    __shared__ float sm[256];
    if (tdx < 128) cnt[tdx] = 0;   // per-m-slab barrier counters
    sm[tdx] = qb2[tdx] + qb2[tdx + 256];
    __syncthreads();
    for (int w = 128; w > 0; w >>= 1) { if (tdx < w) sm[tdx] += sm[tdx + w]; __syncthreads(); }
    if (tdx == 0) b2m[0] = sm[0] * (1.0f / 512.0f);
    __syncthreads();
    sm[tdx] = cb2[tdx] + cb2[tdx + 256];
    __syncthreads();
    for (int w = 128; w > 0; w >>= 1) { if (tdx < w) sm[tdx] += sm[tdx + w]; __syncthreads(); }
    if (tdx == 0) b2m[1] = sm[0] * (1.0f / 512.0f);
  } else if (b < 3077 + 8192) {
    // x -> bf16
    int i = (b - 3077) * 256 + tdx;
    float4 v = x4[i];
    uint2 r;
    r.x = (unsigned)f2bf(v.x) | ((unsigned)f2bf(v.y) << 16);
    r.y = (unsigned)f2bf(v.z) | ((unsigned)f2bf(v.w) << 16);
    xb[i] = r;
  } else {
    // enso tiny MLPs + rowadd zeroing
    int row = (b - 11269) * 256 + tdx;
    rowadd[row] = 0.f;
    float T = x[(size_t)row * 512];
    float H = x[(size_t)row * 512 + 1];
    float fT[5] = {T, H, T * T, T * H, T * T * T};
    float fH[5] = {T, H, T * T, T * H, T * H * H};
    float sT = tb2[0], sH = hb2[0];
#pragma unroll 4
    for (int e = 0; e < 32; ++e) {
      float a1 = tb1[e], a2 = hb1[e];
#pragma unroll
      for (int f = 0; f < 5; ++f) {
        a1 += fT[f] * tW1[f * 32 + e];
        a2 += fH[f] * hW1[f * 32 + e];
      }
      sT += fmaxf(a1, 0.f) * tW2[e];
      sH += fmaxf(a2, 0.f) * hW2[e];
    }
    cT[row] = sT;
    cH[row] = sH;
  }
}

// ---------------------------------------------------------------------------
// GEMM main loop: 128x128 tile, BK=64, global_load_lds(16B) staging.
// LDS layout: row-major 128 x 64 elems (128 B/row = exact bank wrap), 16B
// chunk (row, kc) stored at slot kc ^ (row&7).  Verified conflict-free.
// As/Bs live at kernel scope; macro takes m_base/n_base as parameters.
// Back-to-back invocations are race-free: the k-loop ends with
// __syncthreads() after the last LDS reads.
// ---------------------------------------------------------------------------
#define GEMM_MAINLOOP(A_, Bt_, MB_, NB_)                                          \
  const int tid = threadIdx.x;                                                    \
  const int lane = tid & 63;                                                      \
  const int wave = tid >> 6;                                                      \
  const int wm = wave & 1;                                                        \
  const int wn = wave >> 1;                                                       \
  const int m_base = (MB_);                                                       \
  const int n_base = (NB_);                                                       \
  const int lrow = lane & 15;                                                     \
  const int l7 = lrow & 7;                                                        \
  const int kgrp = lane >> 4;                                                     \
  const int srow = lane >> 3;                                                     \
  const int sk = ((lane & 7) ^ srow) * 8;                                         \
  const unsigned short* gA0 = (A_) + (size_t)(m_base + wave * 8 + srow) * 512 + sk; \
  const unsigned short* gA1 = gA0 + 32 * 512;                                     \
  const unsigned short* gA2 = gA0 + 64 * 512;                                     \
  const unsigned short* gA3 = gA0 + 96 * 512;                                     \
  const unsigned short* gB0 = (Bt_) + (size_t)(n_base + wave * 8 + srow) * 512 + sk;\
  const unsigned short* gB1 = gB0 + 32 * 512;                                     \
  const unsigned short* gB2 = gB0 + 64 * 512;                                     \
  const unsigned short* gB3 = gB0 + 96 * 512;                                     \
  unsigned short* lA0 = As + wave * 512;                                          \
  unsigned short* lA1 = As + (4 + wave) * 512;                                    \
  unsigned short* lA2 = As + (8 + wave) * 512;                                    \
  unsigned short* lA3 = As + (12 + wave) * 512;                                   \
  unsigned short* lB0 = Bs + wave * 512;                                          \
  unsigned short* lB1 = Bs + (4 + wave) * 512;                                    \
  unsigned short* lB2 = Bs + (8 + wave) * 512;                                    \
  unsigned short* lB3 = Bs + (12 + wave) * 512;                                   \
  f32x4 acc[4][4];                                                                \
  _Pragma("unroll") for (int i = 0; i < 4; ++i)                                   \
      _Pragma("unroll") for (int j = 0; j < 4; ++j)                               \
          acc[i][j] = (f32x4){0.f, 0.f, 0.f, 0.f};                                \
  for (int k0 = 0; k0 < 512; k0 += 64) {                                          \
    gload16(gA0, lA0); gload16(gA1, lA1); gload16(gA2, lA2); gload16(gA3, lA3);   \
    gload16(gB0, lB0); gload16(gB1, lB1); gload16(gB2, lB2); gload16(gB3, lB3);   \
    gA0 += 64; gA1 += 64; gA2 += 64; gA3 += 64;                                   \
    gB0 += 64; gB1 += 64; gB2 += 64; gB3 += 64;                                   \
    __syncthreads();                                                              \
    _Pragma("unroll") for (int h = 0; h < 2; ++h) {                               \
      short8 af[4], bfr[4];                                                       \
      const int ks = ((h * 4 + kgrp) ^ l7) * 8;                                   \
      _Pragma("unroll") for (int i = 0; i < 4; ++i)                               \
          af[i] = *(const short8*)(&As[(wm * 64 + i * 16 + lrow) * 64 + ks]);     \
      _Pragma("unroll") for (int j = 0; j < 4; ++j)                               \
          bfr[j] = *(const short8*)(&Bs[(wn * 64 + j * 16 + lrow) * 64 + ks]);    \
      _Pragma("unroll") for (int i = 0; i < 4; ++i)                               \
          _Pragma("unroll") for (int j = 0; j < 4; ++j)                           \
              acc[i][j] = __builtin_amdgcn_mfma_f32_16x16x32_bf16(af[i], bfr[j],  \
                                                                  acc[i][j], 0, 0, 0); \
    }                                                                             \
    __syncthreads();                                                              \
  }

// ---------------------------------------------------------------------------
// Fused GEMM: grid (128, 4). Block (m, g):
//   nl: n-tiles 2g, 2g+1 -> rs accumulate -> rowadd atomics -> cnt[m]++
//   lin: n-tile g k-loop (runs immediately; no wait)
//   spin on cnt[m]==4 (almost always already satisfied) -> epilogue -> out
// ---------------------------------------------------------------------------
__global__ __launch_bounds__(256, 2) void fused_gemm(
    const unsigned short* __restrict__ A,    // xb: 16384 x 512 bf16
    const unsigned short* __restrict__ WT,   // 1536 x 512 bf16 (n-major)
    const float* __restrict__ qb1, const float* __restrict__ cb1,
    const float* __restrict__ qw2m, const float* __restrict__ cw2m,
    float* __restrict__ rowadd, const float* __restrict__ b2m,
    const float* __restrict__ cT, const float* __restrict__ cH,
    float* __restrict__ out, unsigned int* __restrict__ cnt) {
  __shared__ unsigned short As[128 * 64];
  __shared__ unsigned short Bs[128 * 64];
  const unsigned short* Bnl = WT + (size_t)512 * 512;  // rows 512..1535

  // ---- phase nl ----
  float rs[4][4];
#pragma unroll
  for (int i = 0; i < 4; ++i)
#pragma unroll
    for (int r = 0; r < 4; ++r) rs[i][r] = 0.f;

  for (int t = 0; t < 2; ++t) {
    GEMM_MAINLOOP(A, Bnl, blockIdx.x * 128, (blockIdx.y * 2 + t) * 128)
    // C/D: col = lane&15, row = (lane>>4)*4 + reg (m89/m91)
    const bool isq = (n_base < 512);
    const float* b1 = isq ? qb1 : cb1;
    const float* w2m = isq ? qw2m : cw2m;
    const int cb0 = (isq ? n_base : n_base - 512) + wn * 64 + lrow;
#pragma unroll
    for (int j = 0; j < 4; ++j) {
      int col = cb0 + j * 16;
      float bb = b1[col];
      float ww = w2m[col];
#pragma unroll
      for (int i = 0; i < 4; ++i)
#pragma unroll
        for (int r = 0; r < 4; ++r)
          rs[i][r] += fmaxf(acc[i][j][r] + bb, 0.f) * ww;
    }
  }

  {
    const int lane_e = threadIdx.x & 63;
    const int wm_e = (threadIdx.x >> 6) & 1;
    const int rbase = blockIdx.x * 128 + wm_e * 64 + (lane_e >> 4) * 4;
#pragma unroll
    for (int i = 0; i < 4; ++i)
#pragma unroll
      for (int r = 0; r < 4; ++r) {
        float v = rs[i][r];
        v += __shfl_xor(v, 1, 64);
        v += __shfl_xor(v, 2, 64);
        v += __shfl_xor(v, 4, 64);
        v += __shfl_xor(v, 8, 64);
        if ((lane_e & 15) == 0) atomicAdd(&rowadd[rbase + i * 16 + r], v);
      }
  }
  // all threads' rowadd atomics drained at this barrier (vmcnt(0) before
  // s_barrier), then thread 0 publishes this block's completion.
  __syncthreads();
  if (threadIdx.x == 0) {
    __threadfence();
    atomicAdd(&cnt[blockIdx.x], 1u);
  }

  // ---- phase lin (no wait: sync hidden under the k-loop) ----
  {
    GEMM_MAINLOOP(A, WT, blockIdx.x * 128, blockIdx.y * 128)

    // wait for all 4 blocks of this m-slab to have published rowadd
    if (wave == 0) {
      while (__hip_atomic_load(&cnt[blockIdx.x], __ATOMIC_ACQUIRE,
                               __HIP_MEMORY_SCOPE_AGENT) < 4u) {
        __builtin_amdgcn_s_sleep(2);
      }
    }
    __syncthreads();

    const int rbase = m_base + wm * 64 + (lane >> 4) * 4;
    const float b2s = b2m[0] + b2m[1];
    float ra[4][4];
#pragma unroll
    for (int i = 0; i < 4; ++i)
#pragma unroll
      for (int r = 0; r < 4; ++r)
        ra[i][r] = __hip_atomic_load(&rowadd[rbase + i * 16 + r],
                                     __ATOMIC_RELAXED, __HIP_MEMORY_SCOPE_AGENT) + b2s;
#pragma unroll
    for (int j = 0; j < 4; ++j) {
      int col = n_base + wn * 64 + j * 16 + lrow;
#pragma unroll
      for (int i = 0; i < 4; ++i)
#pragma unroll
        for (int r = 0; r < 4; ++r) {
          int row = rbase + i * 16 + r;
          float v = acc[i][j][r] + ra[i][r];
          if (col == 0) v += cT[row];
          if (col == 1) v += cH[row];
          out[(size_t)row * 512 + col] = v;
        }
    }
  }
}

extern "C" void kernel_launch(void* const* d_in, const int* in_sizes, int n_in,
                              void* d_out, int out_size, void* d_ws, size_t ws_size,
                              hipStream_t stream) {
  const float* x   = (const float*)d_in[0];
  const float* t   = (const float*)d_in[1];
  const float* fc  = (const float*)d_in[2];
  const float* qW1 = (const float*)d_in[3];
  const float* qb1 = (const float*)d_in[4];
  const float* qW2 = (const float*)d_in[5];
  const float* qb2 = (const float*)d_in[6];
  const float* cW1 = (const float*)d_in[7];
  const float* cb1 = (const float*)d_in[8];
  const float* cW2 = (const float*)d_in[9];
  const float* cb2 = (const float*)d_in[10];
  const float* tW1 = (const float*)d_in[11];
  const float* tb1 = (const float*)d_in[12];
  const float* tW2 = (const float*)d_in[13];
  const float* tb2 = (const float*)d_in[14];
  const float* hW1 = (const float*)d_in[15];
  const float* hb1 = (const float*)d_in[16];
  const float* hW2 = (const float*)d_in[17];
  const float* hb2 = (const float*)d_in[18];
  float* out = (float*)d_out;

  // workspace layout (bytes); total ~18.6 MB
  char* ws = (char*)d_ws;
  unsigned short* WT = (unsigned short*)(ws);              // 1536*512*2   = 1,572,864
  unsigned short* xb = (unsigned short*)(ws + 1572864);    // 16384*512*2  = 16,777,216
  float* qw2m   = (float*)(ws + 18350080);                 // 512*4
  float* cw2m   = (float*)(ws + 18352128);                 // 512*4
  float* b2m    = (float*)(ws + 18354176);                 // 2*4 (pad)
  float* cT     = (float*)(ws + 18354432);                 // 16384*4
  float* cH     = (float*)(ws + 18419968);                 // 16384*4
  float* rowadd = (float*)(ws + 18485504);                 // 16384*4 -> ends 18,551,040
  unsigned int* cnt = (unsigned int*)(ws + 18551040);      // 128*4 barrier counters

  prep_conv<<<11333, 256, 0, stream>>>(fc, qW1, cW1, t, qW2, cW2, qb2, cb2,
                                       (const float4*)x, x,
                                       tW1, tb1, tW2, tb2, hW1, hb1, hW2, hb2,
                                       WT, (uint2*)xb, qw2m, cw2m, b2m, cT, cH,
                                       rowadd, cnt);
  fused_gemm<<<dim3(128, 4), 256, 0, stream>>>(xb, WT, qb1, cb1, qw2m, cw2m,
                                               rowadd, b2m, cT, cH, out, cnt);
}

// Round 5
// 180.875 us; speedup vs baseline: 1.0093x; 1.0093x over previous
//
#include <hip/hip_runtime.h>

// ---------------------------------------------------------------------------
// out[b,i] = (x@L^T)[b,i] + quad_mean[b] + cubic_mean[b] + (i==0)*cT[b] + (i==1)*cH[b]
// quad_mean[b] = sum_h relu(x@qW1 + qb1)[b,h] * colmean(qW2)[h] + mean(qb2)
//
// Round 12: revert round-11 fusion (spin/fence cost +9us: fused=54.0us vs
// nl+lin~41us inferred; total 182.6 vs 171.7). Keep r3's 3-launch structure.
// ONE change: GEMM k-loop is now 2-PHASE DOUBLE-BUFFERED (T3-minimum):
//   prologue: stage buf0; barrier;
//   step t:   issue stage of buf[t+1] FIRST, then ds_read+MFMA buf[t],
//             then ONE __syncthreads() (vmcnt0 drain covers loads that
//             overlapped a full compute phase -> latency hidden).
// Evidence this is the right regime: r4 counters showed MfmaUtil 18%,
// VALUBusy 11%, HBM 15%, occupancy 17.5% (latency-bound), and r0-vs-r3
// showed more blocks/CU ~= null => stall is the per-step vmcnt(0) drain
// right after load issue. LDS doubles to 64KB -> still 2 blocks/CU.
// Mainloop swizzle (chunk(row,kc)->slot kc^(row&7)), MFMA shape, epilogues
// bit-identical to verified r3 kernel.
// ---------------------------------------------------------------------------

#define OMEGA_F 0.5235987755982988f

typedef __attribute__((ext_vector_type(8))) short short8;
typedef __attribute__((ext_vector_type(4))) float f32x4;

__device__ __forceinline__ unsigned short f2bf(float f) {
  union { float f; unsigned int u; } a;
  a.f = f;
  unsigned int u = a.u;
  return (unsigned short)((u + 0x7fffu + ((u >> 16) & 1u)) >> 16);
}

// async global -> LDS, 16 B per lane; LDS dst wave-uniform, lane i -> base+i*16
__device__ __forceinline__ void gload16(const void* g, void* l) {
  __builtin_amdgcn_global_load_lds(
      (const __attribute__((address_space(1))) unsigned int*)g,
      (__attribute__((address_space(3))) unsigned int*)l, 16, 0, 0);
}

// ---- k1: all prep work in one launch (unchanged, verified) -----------------
__global__ void prep_conv(const float* __restrict__ fc, const float* __restrict__ qW1,
                          const float* __restrict__ cW1, const float* __restrict__ t,
                          const float* __restrict__ qW2, const float* __restrict__ cW2,
                          const float* __restrict__ qb2, const float* __restrict__ cb2,
                          const float4* __restrict__ x4, const float* __restrict__ x,
                          const float* __restrict__ tW1, const float* __restrict__ tb1,
                          const float* __restrict__ tW2, const float* __restrict__ tb2,
                          const float* __restrict__ hW1, const float* __restrict__ hb1,
                          const float* __restrict__ hW2, const float* __restrict__ hb2,
                          unsigned short* __restrict__ WT, uint2* __restrict__ xb,
                          float* __restrict__ qw2m, float* __restrict__ cw2m,
                          float* __restrict__ b2m, float* __restrict__ cT,
                          float* __restrict__ cH, float* __restrict__ rowadd) {
  int b = blockIdx.x, tdx = threadIdx.x;
  if (b < 3072) {
    // WcatT (1536 x 512 bf16, n-major): [ L | quad_W1^T | cubic_W1^T ]
    int idx = b * 256 + tdx;
    int n = idx >> 9;
    int k = idx & 511;
    float v;
    if (n < 512) {
      float th = OMEGA_F * t[0];
      float s1, c1, s2, c2;
      sincosf(th, &s1, &c1);
      sincosf(2.0f * th, &s2, &c2);
      const float* p = fc + ((size_t)n * 512 + k) * 5;
      v = p[0] + p[1] * c1 + p[2] * s1 + p[3] * c2 + p[4] * s2;
    } else if (n < 1024) {
      v = qW1[(size_t)k * 512 + (n - 512)];
    } else {
      v = cW1[(size_t)k * 512 + (n - 1024)];
    }
    WT[idx] = f2bf(v);
  } else if (b < 3076) {
    int bb = b - 3072;
    const float* W = (bb < 2) ? qW2 : cW2;
    float* o = (bb < 2) ? qw2m : cw2m;
    int h = (bb & 1) * 256 + tdx;
    const float4* row = (const float4*)(W + (size_t)h * 512);
    float s = 0.f;
    for (int i = 0; i < 128; ++i) { float4 v = row[i]; s += (v.x + v.y) + (v.z + v.w); }
    o[h] = s * (1.0f / 512.0f);
  } else if (b == 3076) {
    __shared__ float sm[256];
    sm[tdx] = qb2[tdx] + qb2[tdx + 256];
    __syncthreads();
    for (int w = 128; w > 0; w >>= 1) { if (tdx < w) sm[tdx] += sm[tdx + w]; __syncthreads(); }
    if (tdx == 0) b2m[0] = sm[0] * (1.0f / 512.0f);
    __syncthreads();
    sm[tdx] = cb2[tdx] + cb2[tdx + 256];
    __syncthreads();
    for (int w = 128; w > 0; w >>= 1) { if (tdx < w) sm[tdx] += sm[tdx + w]; __syncthreads(); }
    if (tdx == 0) b2m[1] = sm[0] * (1.0f / 512.0f);
  } else if (b < 3077 + 8192) {
    // x -> bf16
    int i = (b - 3077) * 256 + tdx;
    float4 v = x4[i];
    uint2 r;
    r.x = (unsigned)f2bf(v.x) | ((unsigned)f2bf(v.y) << 16);
    r.y = (unsigned)f2bf(v.z) | ((unsigned)f2bf(v.w) << 16);
    xb[i] = r;
  } else {
    // enso tiny MLPs + rowadd zeroing
    int row = (b - 11269) * 256 + tdx;
    rowadd[row] = 0.f;
    float T = x[(size_t)row * 512];
    float H = x[(size_t)row * 512 + 1];
    float fT[5] = {T, H, T * T, T * H, T * T * T};
    float fH[5] = {T, H, T * T, T * H, T * H * H};
    float sT = tb2[0], sH = hb2[0];
#pragma unroll 4
    for (int e = 0; e < 32; ++e) {
      float a1 = tb1[e], a2 = hb1[e];
#pragma unroll
      for (int f = 0; f < 5; ++f) {
        a1 += fT[f] * tW1[f * 32 + e];
        a2 += fH[f] * hW1[f * 32 + e];
      }
      sT += fmaxf(a1, 0.f) * tW2[e];
      sH += fmaxf(a2, 0.f) * hW2[e];
    }
    cT[row] = sT;
    cH[row] = sH;
  }
}

// ---------------------------------------------------------------------------
// 2-phase double-buffered GEMM main loop: 128x128 tile, BK=64,
// global_load_lds(16B) staging into As/Bs[2][128*64] (8192-elem halves).
// LDS layout per buffer: row-major 128 x 64 elems, 16B chunk (row, kc) at
// slot kc ^ (row&7) (verified conflict-free).
// Race-freedom with ONE barrier per step: buf X written at step t is read
// at t+1 (after the t-barrier's vmcnt(0) drain); the next write to X is
// issued at t+2, after the (t+1)-barrier confirms all reads of X are done.
// Caller declares As/Bs[2*8192]; macro takes m_base/n_base as parameters.
// ---------------------------------------------------------------------------
#define GEMM_MAINLOOP(A_, Bt_, MB_, NB_)                                          \
  const int tid = threadIdx.x;                                                    \
  const int lane = tid & 63;                                                      \
  const int wave = tid >> 6;                                                      \
  const int wm = wave & 1;                                                        \
  const int wn = wave >> 1;                                                       \
  const int m_base = (MB_);                                                       \
  const int n_base = (NB_);                                                       \
  const int lrow = lane & 15;                                                     \
  const int l7 = lrow & 7;                                                        \
  const int kgrp = lane >> 4;                                                     \
  const int srow = lane >> 3;                                                     \
  const int sk = ((lane & 7) ^ srow) * 8;                                         \
  const unsigned short* gA0 = (A_) + (size_t)(m_base + wave * 8 + srow) * 512 + sk; \
  const unsigned short* gA1 = gA0 + 32 * 512;                                     \
  const unsigned short* gA2 = gA0 + 64 * 512;                                     \
  const unsigned short* gA3 = gA0 + 96 * 512;                                     \
  const unsigned short* gB0 = (Bt_) + (size_t)(n_base + wave * 8 + srow) * 512 + sk;\
  const unsigned short* gB1 = gB0 + 32 * 512;                                     \
  const unsigned short* gB2 = gB0 + 64 * 512;                                     \
  const unsigned short* gB3 = gB0 + 96 * 512;                                     \
  unsigned short* lA0 = As + wave * 512;                                          \
  unsigned short* lA1 = As + (4 + wave) * 512;                                    \
  unsigned short* lA2 = As + (8 + wave) * 512;                                    \
  unsigned short* lA3 = As + (12 + wave) * 512;                                   \
  unsigned short* lB0 = Bs + wave * 512;                                          \
  unsigned short* lB1 = Bs + (4 + wave) * 512;                                    \
  unsigned short* lB2 = Bs + (8 + wave) * 512;                                    \
  unsigned short* lB3 = Bs + (12 + wave) * 512;                                   \
  f32x4 acc[4][4];                                                                \
  _Pragma("unroll") for (int i = 0; i < 4; ++i)                                   \
      _Pragma("unroll") for (int j = 0; j < 4; ++j)                               \
          acc[i][j] = (f32x4){0.f, 0.f, 0.f, 0.f};                                \
  gload16(gA0, lA0); gload16(gA1, lA1); gload16(gA2, lA2); gload16(gA3, lA3);     \
  gload16(gB0, lB0); gload16(gB1, lB1); gload16(gB2, lB2); gload16(gB3, lB3);     \
  gA0 += 64; gA1 += 64; gA2 += 64; gA3 += 64;                                     \
  gB0 += 64; gB1 += 64; gB2 += 64; gB3 += 64;                                     \
  __syncthreads();                                                                \
  _Pragma("unroll") for (int kt = 0; kt < 8; ++kt) {                              \
    const int cur = (kt & 1) << 13;                                               \
    const int nxt = cur ^ 8192;                                                   \
    if (kt < 7) {                                                                 \
      gload16(gA0, lA0 + nxt); gload16(gA1, lA1 + nxt);                           \
      gload16(gA2, lA2 + nxt); gload16(gA3, lA3 + nxt);                           \
      gload16(gB0, lB0 + nxt); gload16(gB1, lB1 + nxt);                           \
      gload16(gB2, lB2 + nxt); gload16(gB3, lB3 + nxt);                           \
      gA0 += 64; gA1 += 64; gA2 += 64; gA3 += 64;                                 \
      gB0 += 64; gB1 += 64; gB2 += 64; gB3 += 64;                                 \
    }                                                                             \
    _Pragma("unroll") for (int h = 0; h < 2; ++h) {                               \
      short8 af[4], bfr[4];                                                       \
      const int ks = ((h * 4 + kgrp) ^ l7) * 8 + cur;                             \
      _Pragma("unroll") for (int i = 0; i < 4; ++i)                               \
          af[i] = *(const short8*)(&As[(wm * 64 + i * 16 + lrow) * 64 + ks]);     \
      _Pragma("unroll") for (int j = 0; j < 4; ++j)                               \
          bfr[j] = *(const short8*)(&Bs[(wn * 64 + j * 16 + lrow) * 64 + ks]);    \
      _Pragma("unroll") for (int i = 0; i < 4; ++i)                               \
          _Pragma("unroll") for (int j = 0; j < 4; ++j)                           \
              acc[i][j] = __builtin_amdgcn_mfma_f32_16x16x32_bf16(af[i], bfr[j],  \
                                                                  acc[i][j], 0, 0, 0); \
    }                                                                             \
    __syncthreads();                                                              \
  }

// ---- phase 1: x @ [qW1 | cW1] -> relu.w2m row reduction -> rowadd ----------
// grid (128, 4): block (x,y) computes n-tiles 2y and 2y+1 of m-slab x.
__global__ __launch_bounds__(256) void nl_gemm(
    const unsigned short* __restrict__ A,    // 16384 x 512 bf16
    const unsigned short* __restrict__ Bt,   // 1024 x 512 bf16 (WT rows 512..1535)
    const float* __restrict__ qb1, const float* __restrict__ cb1,
    const float* __restrict__ qw2m, const float* __restrict__ cw2m,
    float* __restrict__ rowadd) {
  __shared__ unsigned short As[2 * 128 * 64];
  __shared__ unsigned short Bs[2 * 128 * 64];
  float rs[4][4];
#pragma unroll
  for (int i = 0; i < 4; ++i)
#pragma unroll
    for (int r = 0; r < 4; ++r) rs[i][r] = 0.f;

  for (int t = 0; t < 2; ++t) {
    GEMM_MAINLOOP(A, Bt, blockIdx.x * 128, (blockIdx.y * 2 + t) * 128)
    // C/D: col = lane&15, row = (lane>>4)*4 + reg (m89/m91)
    const bool isq = (n_base < 512);
    const float* b1 = isq ? qb1 : cb1;
    const float* w2m = isq ? qw2m : cw2m;
    const int cb0 = (isq ? n_base : n_base - 512) + wn * 64 + lrow;
#pragma unroll
    for (int j = 0; j < 4; ++j) {
      int col = cb0 + j * 16;
      float bb = b1[col];
      float ww = w2m[col];
#pragma unroll
      for (int i = 0; i < 4; ++i)
#pragma unroll
        for (int r = 0; r < 4; ++r)
          rs[i][r] += fmaxf(acc[i][j][r] + bb, 0.f) * ww;
    }
  }

  // one reduction + atomic pass for both tiles (rows identical across tiles)
  const int lane_e = threadIdx.x & 63;
  const int wm_e = (threadIdx.x >> 6) & 1;
  const int rbase = blockIdx.x * 128 + wm_e * 64 + (lane_e >> 4) * 4;
#pragma unroll
  for (int i = 0; i < 4; ++i)
#pragma unroll
    for (int r = 0; r < 4; ++r) {
      float v = rs[i][r];
      v += __shfl_xor(v, 1, 64);
      v += __shfl_xor(v, 2, 64);
      v += __shfl_xor(v, 4, 64);
      v += __shfl_xor(v, 8, 64);
      if ((lane_e & 15) == 0) atomicAdd(&rowadd[rbase + i * 16 + r], v);
    }
}

// ---- phase 2: x @ L^T, epilogue folds rowadd + b2 means + enso -> out ------
__global__ __launch_bounds__(256) void lin_gemm(
    const unsigned short* __restrict__ A,    // 16384 x 512 bf16
    const unsigned short* __restrict__ Bt,   // 512 x 512 bf16 (WT rows 0..511)
    const float* __restrict__ rowadd, const float* __restrict__ b2m,
    const float* __restrict__ cT, const float* __restrict__ cH,
    float* __restrict__ out) {
  __shared__ unsigned short As[2 * 128 * 64];
  __shared__ unsigned short Bs[2 * 128 * 64];
  GEMM_MAINLOOP(A, Bt, blockIdx.x * 128, blockIdx.y * 128)
  const int rbase = m_base + wm * 64 + (lane >> 4) * 4;
  const float b2s = b2m[0] + b2m[1];
  float ra[4][4];
#pragma unroll
  for (int i = 0; i < 4; ++i)
#pragma unroll
    for (int r = 0; r < 4; ++r) ra[i][r] = rowadd[rbase + i * 16 + r] + b2s;
#pragma unroll
  for (int j = 0; j < 4; ++j) {
    int col = n_base + wn * 64 + j * 16 + lrow;
#pragma unroll
    for (int i = 0; i < 4; ++i)
#pragma unroll
      for (int r = 0; r < 4; ++r) {
        int row = rbase + i * 16 + r;
        float v = acc[i][j][r] + ra[i][r];
        if (col == 0) v += cT[row];
        if (col == 1) v += cH[row];
        out[(size_t)row * 512 + col] = v;
      }
  }
}

extern "C" void kernel_launch(void* const* d_in, const int* in_sizes, int n_in,
                              void* d_out, int out_size, void* d_ws, size_t ws_size,
                              hipStream_t stream) {
  const float* x   = (const float*)d_in[0];
  const float* t   = (const float*)d_in[1];
  const float* fc  = (const float*)d_in[2];
  const float* qW1 = (const float*)d_in[3];
  const float* qb1 = (const float*)d_in[4];
  const float* qW2 = (const float*)d_in[5];
  const float* qb2 = (const float*)d_in[6];
  const float* cW1 = (const float*)d_in[7];
  const float* cb1 = (const float*)d_in[8];
  const float* cW2 = (const float*)d_in[9];
  const float* cb2 = (const float*)d_in[10];
  const float* tW1 = (const float*)d_in[11];
  const float* tb1 = (const float*)d_in[12];
  const float* tW2 = (const float*)d_in[13];
  const float* tb2 = (const float*)d_in[14];
  const float* hW1 = (const float*)d_in[15];
  const float* hb1 = (const float*)d_in[16];
  const float* hW2 = (const float*)d_in[17];
  const float* hb2 = (const float*)d_in[18];
  float* out = (float*)d_out;

  // workspace layout (bytes); total ~18.6 MB
  char* ws = (char*)d_ws;
  unsigned short* WT = (unsigned short*)(ws);              // 1536*512*2   = 1,572,864
  unsigned short* xb = (unsigned short*)(ws + 1572864);    // 16384*512*2  = 16,777,216
  float* qw2m   = (float*)(ws + 18350080);                 // 512*4
  float* cw2m   = (float*)(ws + 18352128);                 // 512*4
  float* b2m    = (float*)(ws + 18354176);                 // 2*4 (pad)
  float* cT     = (float*)(ws + 18354432);                 // 16384*4
  float* cH     = (float*)(ws + 18419968);                 // 16384*4
  float* rowadd = (float*)(ws + 18485504);                 // 16384*4 -> ends 18,551,040

  prep_conv<<<11333, 256, 0, stream>>>(fc, qW1, cW1, t, qW2, cW2, qb2, cb2,
                                       (const float4*)x, x,
                                       tW1, tb1, tW2, tb2, hW1, hb1, hW2, hb2,
                                       WT, (uint2*)xb, qw2m, cw2m, b2m, cT, cH,
                                       rowadd);
  nl_gemm<<<dim3(128, 4), 256, 0, stream>>>(xb, WT + (size_t)512 * 512,
                                            qb1, cb1, qw2m, cw2m, rowadd);
  lin_gemm<<<dim3(128, 4), 256, 0, stream>>>(xb, WT, rowadd, b2m, cT, cH, out);
}

// Round 6
// 176.992 us; speedup vs baseline: 1.0315x; 1.0219x over previous
//
#include <hip/hip_runtime.h>

// ---------------------------------------------------------------------------
// out[b,i] = (x@L^T)[b,i] + quad_mean[b] + cubic_mean[b] + (i==0)*cT[b] + (i==1)*cH[b]
// quad_mean[b] = sum_h relu(x@qW1 + qb1)[b,h] * colmean(qW2)[h] + mean(qb2)
//
// Round 13: r5's dbuf regressed because each step still ended in
// __syncthreads() = vmcnt(0) drain of the JUST-issued prefetch (T3 without
// T4; m218: pipeline-with-drain0 ~= no pipeline). This round keeps the dbuf
// skeleton but replaces both per-step syncs with raw s_barrier + COUNTED
// s_waitcnt vmcnt(8) (vmcnt(0) only at the last step). 2-deep pipeline:
// prologue stages S0,S1; step t waits S(t) (issued 2 steps ago -> ~0 stall),
// computes buf[t&1], barrier, then stages S(t+2) into buf[t&1].
// Race-freedom: writes to a buffer are issued only after the post-compute
// barrier that all readers passed; ds_reads retire before that barrier
// (each feeds an MFMA preceding it). Compiler motion fenced with "memory"
// asm (rule #18). Swizzle/fragments/epilogues/grids identical to r3.
// ---------------------------------------------------------------------------

#define OMEGA_F 0.5235987755982988f

typedef __attribute__((ext_vector_type(8))) short short8;
typedef __attribute__((ext_vector_type(4))) float f32x4;

__device__ __forceinline__ unsigned short f2bf(float f) {
  union { float f; unsigned int u; } a;
  a.f = f;
  unsigned int u = a.u;
  return (unsigned short)((u + 0x7fffu + ((u >> 16) & 1u)) >> 16);
}

// async global -> LDS, 16 B per lane; LDS dst wave-uniform, lane i -> base+i*16
__device__ __forceinline__ void gload16(const void* g, void* l) {
  __builtin_amdgcn_global_load_lds(
      (const __attribute__((address_space(1))) unsigned int*)g,
      (__attribute__((address_space(3))) unsigned int*)l, 16, 0, 0);
}

// ---- k1: all prep work in one launch (unchanged, verified) -----------------
__global__ void prep_conv(const float* __restrict__ fc, const float* __restrict__ qW1,
                          const float* __restrict__ cW1, const float* __restrict__ t,
                          const float* __restrict__ qW2, const float* __restrict__ cW2,
                          const float* __restrict__ qb2, const float* __restrict__ cb2,
                          const float4* __restrict__ x4, const float* __restrict__ x,
                          const float* __restrict__ tW1, const float* __restrict__ tb1,
                          const float* __restrict__ tW2, const float* __restrict__ tb2,
                          const float* __restrict__ hW1, const float* __restrict__ hb1,
                          const float* __restrict__ hW2, const float* __restrict__ hb2,
                          unsigned short* __restrict__ WT, uint2* __restrict__ xb,
                          float* __restrict__ qw2m, float* __restrict__ cw2m,
                          float* __restrict__ b2m, float* __restrict__ cT,
                          float* __restrict__ cH, float* __restrict__ rowadd) {
  int b = blockIdx.x, tdx = threadIdx.x;
  if (b < 3072) {
    // WcatT (1536 x 512 bf16, n-major): [ L | quad_W1^T | cubic_W1^T ]
    int idx = b * 256 + tdx;
    int n = idx >> 9;
    int k = idx & 511;
    float v;
    if (n < 512) {
      float th = OMEGA_F * t[0];
      float s1, c1, s2, c2;
      sincosf(th, &s1, &c1);
      sincosf(2.0f * th, &s2, &c2);
      const float* p = fc + ((size_t)n * 512 + k) * 5;
      v = p[0] + p[1] * c1 + p[2] * s1 + p[3] * c2 + p[4] * s2;
    } else if (n < 1024) {
      v = qW1[(size_t)k * 512 + (n - 512)];
    } else {
      v = cW1[(size_t)k * 512 + (n - 1024)];
    }
    WT[idx] = f2bf(v);
  } else if (b < 3076) {
    int bb = b - 3072;
    const float* W = (bb < 2) ? qW2 : cW2;
    float* o = (bb < 2) ? qw2m : cw2m;
    int h = (bb & 1) * 256 + tdx;
    const float4* row = (const float4*)(W + (size_t)h * 512);
    float s = 0.f;
    for (int i = 0; i < 128; ++i) { float4 v = row[i]; s += (v.x + v.y) + (v.z + v.w); }
    o[h] = s * (1.0f / 512.0f);
  } else if (b == 3076) {
    __shared__ float sm[256];
    sm[tdx] = qb2[tdx] + qb2[tdx + 256];
    __syncthreads();
    for (int w = 128; w > 0; w >>= 1) { if (tdx < w) sm[tdx] += sm[tdx + w]; __syncthreads(); }
    if (tdx == 0) b2m[0] = sm[0] * (1.0f / 512.0f);
    __syncthreads();
    sm[tdx] = cb2[tdx] + cb2[tdx + 256];
    __syncthreads();
    for (int w = 128; w > 0; w >>= 1) { if (tdx < w) sm[tdx] += sm[tdx + w]; __syncthreads(); }
    if (tdx == 0) b2m[1] = sm[0] * (1.0f / 512.0f);
  } else if (b < 3077 + 8192) {
    // x -> bf16
    int i = (b - 3077) * 256 + tdx;
    float4 v = x4[i];
    uint2 r;
    r.x = (unsigned)f2bf(v.x) | ((unsigned)f2bf(v.y) << 16);
    r.y = (unsigned)f2bf(v.z) | ((unsigned)f2bf(v.w) << 16);
    xb[i] = r;
  } else {
    // enso tiny MLPs + rowadd zeroing
    int row = (b - 11269) * 256 + tdx;
    rowadd[row] = 0.f;
    float T = x[(size_t)row * 512];
    float H = x[(size_t)row * 512 + 1];
    float fT[5] = {T, H, T * T, T * H, T * T * T};
    float fH[5] = {T, H, T * T, T * H, T * H * H};
    float sT = tb2[0], sH = hb2[0];
#pragma unroll 4
    for (int e = 0; e < 32; ++e) {
      float a1 = tb1[e], a2 = hb1[e];
#pragma unroll
      for (int f = 0; f < 5; ++f) {
        a1 += fT[f] * tW1[f * 32 + e];
        a2 += fH[f] * hW1[f * 32 + e];
      }
      sT += fmaxf(a1, 0.f) * tW2[e];
      sH += fmaxf(a2, 0.f) * hW2[e];
    }
    cT[row] = sT;
    cH[row] = sH;
  }
}

// ---------------------------------------------------------------------------
// Counted-vmcnt double-buffered GEMM main loop: 128x128 tile, BK=64,
// global_load_lds(16B) into As/Bs[2][8192]. Per-buffer LDS layout:
// row-major 128x64 elems, 16B chunk (row,kc) at slot kc^(row&7)
// (verified conflict-free).
// Pipeline (2-deep): stage S0,S1; step t: vmcnt(8) [t==7: vmcnt(0)] ->
// s_barrier -> compute buf[t&1] -> s_barrier -> stage S(t+2) into buf[t&1]
// (t<6). vmcnt(8) leaves the 8 newest loads (S(t+1)) in flight: T4.
// ---------------------------------------------------------------------------
#define GEMM_STAGE(off)                                                           \
  gload16(gA0, lA0 + (off)); gload16(gA1, lA1 + (off));                           \
  gload16(gA2, lA2 + (off)); gload16(gA3, lA3 + (off));                           \
  gload16(gB0, lB0 + (off)); gload16(gB1, lB1 + (off));                           \
  gload16(gB2, lB2 + (off)); gload16(gB3, lB3 + (off));                           \
  gA0 += 64; gA1 += 64; gA2 += 64; gA3 += 64;                                     \
  gB0 += 64; gB1 += 64; gB2 += 64; gB3 += 64;

#define GEMM_MAINLOOP(A_, Bt_, MB_, NB_)                                          \
  const int tid = threadIdx.x;                                                    \
  const int lane = tid & 63;                                                      \
  const int wave = tid >> 6;                                                      \
  const int wm = wave & 1;                                                        \
  const int wn = wave >> 1;                                                       \
  const int m_base = (MB_);                                                       \
  const int n_base = (NB_);                                                       \
  const int lrow = lane & 15;                                                     \
  const int l7 = lrow & 7;                                                        \
  const int kgrp = lane >> 4;                                                     \
  const int srow = lane >> 3;                                                     \
  const int sk = ((lane & 7) ^ srow) * 8;                                         \
  const unsigned short* gA0 = (A_) + (size_t)(m_base + wave * 8 + srow) * 512 + sk; \
  const unsigned short* gA1 = gA0 + 32 * 512;                                     \
  const unsigned short* gA2 = gA0 + 64 * 512;                                     \
  const unsigned short* gA3 = gA0 + 96 * 512;                                     \
  const unsigned short* gB0 = (Bt_) + (size_t)(n_base + wave * 8 + srow) * 512 + sk;\
  const unsigned short* gB1 = gB0 + 32 * 512;                                     \
  const unsigned short* gB2 = gB0 + 64 * 512;                                     \
  const unsigned short* gB3 = gB0 + 96 * 512;                                     \
  unsigned short* lA0 = As + wave * 512;                                          \
  unsigned short* lA1 = As + (4 + wave) * 512;                                    \
  unsigned short* lA2 = As + (8 + wave) * 512;                                    \
  unsigned short* lA3 = As + (12 + wave) * 512;                                   \
  unsigned short* lB0 = Bs + wave * 512;                                          \
  unsigned short* lB1 = Bs + (4 + wave) * 512;                                    \
  unsigned short* lB2 = Bs + (8 + wave) * 512;                                    \
  unsigned short* lB3 = Bs + (12 + wave) * 512;                                   \
  f32x4 acc[4][4];                                                                \
  _Pragma("unroll") for (int i = 0; i < 4; ++i)                                   \
      _Pragma("unroll") for (int j = 0; j < 4; ++j)                               \
          acc[i][j] = (f32x4){0.f, 0.f, 0.f, 0.f};                                \
  GEMM_STAGE(0)                                                                   \
  GEMM_STAGE(8192)                                                                \
  _Pragma("unroll") for (int kt = 0; kt < 8; ++kt) {                              \
    const int cur = (kt & 1) << 13;                                               \
    if (kt == 7) { asm volatile("s_waitcnt vmcnt(0)" ::: "memory"); }             \
    else         { asm volatile("s_waitcnt vmcnt(8)" ::: "memory"); }             \
    __builtin_amdgcn_s_barrier();                                                 \
    asm volatile("" ::: "memory");                                                \
    _Pragma("unroll") for (int h = 0; h < 2; ++h) {                               \
      short8 af[4], bfr[4];                                                       \
      const int ks = ((h * 4 + kgrp) ^ l7) * 8 + cur;                             \
      _Pragma("unroll") for (int i = 0; i < 4; ++i)                               \
          af[i] = *(const short8*)(&As[(wm * 64 + i * 16 + lrow) * 64 + ks]);     \
      _Pragma("unroll") for (int j = 0; j < 4; ++j)                               \
          bfr[j] = *(const short8*)(&Bs[(wn * 64 + j * 16 + lrow) * 64 + ks]);    \
      _Pragma("unroll") for (int i = 0; i < 4; ++i)                               \
          _Pragma("unroll") for (int j = 0; j < 4; ++j)                           \
              acc[i][j] = __builtin_amdgcn_mfma_f32_16x16x32_bf16(af[i], bfr[j],  \
                                                                  acc[i][j], 0, 0, 0); \
    }                                                                             \
    asm volatile("" ::: "memory");                                                \
    __builtin_amdgcn_s_barrier();                                                 \
    asm volatile("" ::: "memory");                                                \
    if (kt < 6) { GEMM_STAGE(cur) }                                               \
  }

// ---- phase 1: x @ [qW1 | cW1] -> relu.w2m row reduction -> rowadd ----------
// grid (128, 4): block (x,y) computes n-tiles 2y and 2y+1 of m-slab x.
__global__ __launch_bounds__(256) void nl_gemm(
    const unsigned short* __restrict__ A,    // 16384 x 512 bf16
    const unsigned short* __restrict__ Bt,   // 1024 x 512 bf16 (WT rows 512..1535)
    const float* __restrict__ qb1, const float* __restrict__ cb1,
    const float* __restrict__ qw2m, const float* __restrict__ cw2m,
    float* __restrict__ rowadd) {
  __shared__ unsigned short As[2 * 128 * 64];
  __shared__ unsigned short Bs[2 * 128 * 64];
  float rs[4][4];
#pragma unroll
  for (int i = 0; i < 4; ++i)
#pragma unroll
    for (int r = 0; r < 4; ++r) rs[i][r] = 0.f;

  for (int t = 0; t < 2; ++t) {
    GEMM_MAINLOOP(A, Bt, blockIdx.x * 128, (blockIdx.y * 2 + t) * 128)
    // C/D: col = lane&15, row = (lane>>4)*4 + reg (m89/m91)
    const bool isq = (n_base < 512);
    const float* b1 = isq ? qb1 : cb1;
    const float* w2m = isq ? qw2m : cw2m;
    const int cb0 = (isq ? n_base : n_base - 512) + wn * 64 + lrow;
#pragma unroll
    for (int j = 0; j < 4; ++j) {
      int col = cb0 + j * 16;
      float bb = b1[col];
      float ww = w2m[col];
#pragma unroll
      for (int i = 0; i < 4; ++i)
#pragma unroll
        for (int r = 0; r < 4; ++r)
          rs[i][r] += fmaxf(acc[i][j][r] + bb, 0.f) * ww;
    }
  }

  // one reduction + atomic pass for both tiles (rows identical across tiles)
  const int lane_e = threadIdx.x & 63;
  const int wm_e = (threadIdx.x >> 6) & 1;
  const int rbase = blockIdx.x * 128 + wm_e * 64 + (lane_e >> 4) * 4;
#pragma unroll
  for (int i = 0; i < 4; ++i)
#pragma unroll
    for (int r = 0; r < 4; ++r) {
      float v = rs[i][r];
      v += __shfl_xor(v, 1, 64);
      v += __shfl_xor(v, 2, 64);
      v += __shfl_xor(v, 4, 64);
      v += __shfl_xor(v, 8, 64);
      if ((lane_e & 15) == 0) atomicAdd(&rowadd[rbase + i * 16 + r], v);
    }
}

// ---- phase 2: x @ L^T, epilogue folds rowadd + b2 means + enso -> out ------
__global__ __launch_bounds__(256) void lin_gemm(
    const unsigned short* __restrict__ A,    // 16384 x 512 bf16
    const unsigned short* __restrict__ Bt,   // 512 x 512 bf16 (WT rows 0..511)
    const float* __restrict__ rowadd, const float* __restrict__ b2m,
    const float* __restrict__ cT, const float* __restrict__ cH,
    float* __restrict__ out) {
  __shared__ unsigned short As[2 * 128 * 64];
  __shared__ unsigned short Bs[2 * 128 * 64];
  GEMM_MAINLOOP(A, Bt, blockIdx.x * 128, blockIdx.y * 128)
  const int rbase = m_base + wm * 64 + (lane >> 4) * 4;
  const float b2s = b2m[0] + b2m[1];
  float ra[4][4];
#pragma unroll
  for (int i = 0; i < 4; ++i)
#pragma unroll
    for (int r = 0; r < 4; ++r) ra[i][r] = rowadd[rbase + i * 16 + r] + b2s;
#pragma unroll
  for (int j = 0; j < 4; ++j) {
    int col = n_base + wn * 64 + j * 16 + lrow;
#pragma unroll
    for (int i = 0; i < 4; ++i)
#pragma unroll
      for (int r = 0; r < 4; ++r) {
        int row = rbase + i * 16 + r;
        float v = acc[i][j][r] + ra[i][r];
        if (col == 0) v += cT[row];
        if (col == 1) v += cH[row];
        out[(size_t)row * 512 + col] = v;
      }
  }
}

extern "C" void kernel_launch(void* const* d_in, const int* in_sizes, int n_in,
                              void* d_out, int out_size, void* d_ws, size_t ws_size,
                              hipStream_t stream) {
  const float* x   = (const float*)d_in[0];
  const float* t   = (const float*)d_in[1];
  const float* fc  = (const float*)d_in[2];
  const float* qW1 = (const float*)d_in[3];
  const float* qb1 = (const float*)d_in[4];
  const float* qW2 = (const float*)d_in[5];
  const float* qb2 = (const float*)d_in[6];
  const float* cW1 = (const float*)d_in[7];
  const float* cb1 = (const float*)d_in[8];
  const float* cW2 = (const float*)d_in[9];
  const float* cb2 = (const float*)d_in[10];
  const float* tW1 = (const float*)d_in[11];
  const float* tb1 = (const float*)d_in[12];
  const float* tW2 = (const float*)d_in[13];
  const float* tb2 = (const float*)d_in[14];
  const float* hW1 = (const float*)d_in[15];
  const float* hb1 = (const float*)d_in[16];
  const float* hW2 = (const float*)d_in[17];
  const float* hb2 = (const float*)d_in[18];
  float* out = (float*)d_out;

  // workspace layout (bytes); total ~18.6 MB
  char* ws = (char*)d_ws;
  unsigned short* WT = (unsigned short*)(ws);              // 1536*512*2   = 1,572,864
  unsigned short* xb = (unsigned short*)(ws + 1572864);    // 16384*512*2  = 16,777,216
  float* qw2m   = (float*)(ws + 18350080);                 // 512*4
  float* cw2m   = (float*)(ws + 18352128);                 // 512*4
  float* b2m    = (float*)(ws + 18354176);                 // 2*4 (pad)
  float* cT     = (float*)(ws + 18354432);                 // 16384*4
  float* cH     = (float*)(ws + 18419968);                 // 16384*4
  float* rowadd = (float*)(ws + 18485504);                 // 16384*4 -> ends 18,551,040

  prep_conv<<<11333, 256, 0, stream>>>(fc, qW1, cW1, t, qW2, cW2, qb2, cb2,
                                       (const float4*)x, x,
                                       tW1, tb1, tW2, tb2, hW1, hb1, hW2, hb2,
                                       WT, (uint2*)xb, qw2m, cw2m, b2m, cT, cH,
                                       rowadd);
  nl_gemm<<<dim3(128, 4), 256, 0, stream>>>(xb, WT + (size_t)512 * 512,
                                            qb1, cb1, qw2m, cw2m, rowadd);
  lin_gemm<<<dim3(128, 4), 256, 0, stream>>>(xb, WT, rowadd, b2m, cT, cH, out);
}

// Round 7
// 169.499 us; speedup vs baseline: 1.0771x; 1.0442x over previous
//
#include <hip/hip_runtime.h>

// ---------------------------------------------------------------------------
// out[b,i] = (x@L^T)[b,i] + quad_mean[b] + cubic_mean[b] + (i==0)*cT[b] + (i==1)*cH[b]
// quad_mean[b] = sum_h relu(x@qW1 + qb1)[b,h] * colmean(qW2)[h] + mean(qb2)
//
// Round 14: pipelining verdict after r4/r5/r6 (fused 182.6, dbuf-drain0
// 180.9, dbuf-counted 177.0 vs plain 171.7): with 2 blocks/CU the implicit
// cross-block overlap already hides staging latency; explicit schedules only
// add overhead at this 128^2 structure. KEEP r3's plain 2-barrier loop.
// This round's single change targets the MFMA:staging ratio instead
// (m93 lever): nl_gemm's two n-tiles share one A-slab -> ONE k-loop computes
// the 128x256 pair with LDS {A,B0,B1} (48KB, single-buffered):
//   per K-step: 12 gloads (was 2x8), 64 MFMA (was 2x32), barriers halved,
//   A ds_reads halved, A global traffic halved.
// __launch_bounds__(256,2) caps VGPR<=256 (acc=128 regs) -> 2 blocks/CU
// resident for grid 512. Epilogue folds both tiles into rs[4][4]; one
// reduce+atomic pass. Tile pairs never straddle q/c boundary (y<2 <=> quad).
// lin_gemm + prep_conv bit-identical to verified r3 (171.7us).
// ---------------------------------------------------------------------------

#define OMEGA_F 0.5235987755982988f

typedef __attribute__((ext_vector_type(8))) short short8;
typedef __attribute__((ext_vector_type(4))) float f32x4;

__device__ __forceinline__ unsigned short f2bf(float f) {
  union { float f; unsigned int u; } a;
  a.f = f;
  unsigned int u = a.u;
  return (unsigned short)((u + 0x7fffu + ((u >> 16) & 1u)) >> 16);
}

// async global -> LDS, 16 B per lane; LDS dst wave-uniform, lane i -> base+i*16
__device__ __forceinline__ void gload16(const void* g, void* l) {
  __builtin_amdgcn_global_load_lds(
      (const __attribute__((address_space(1))) unsigned int*)g,
      (__attribute__((address_space(3))) unsigned int*)l, 16, 0, 0);
}

// ---- k1: all prep work in one launch (unchanged, verified) -----------------
__global__ void prep_conv(const float* __restrict__ fc, const float* __restrict__ qW1,
                          const float* __restrict__ cW1, const float* __restrict__ t,
                          const float* __restrict__ qW2, const float* __restrict__ cW2,
                          const float* __restrict__ qb2, const float* __restrict__ cb2,
                          const float4* __restrict__ x4, const float* __restrict__ x,
                          const float* __restrict__ tW1, const float* __restrict__ tb1,
                          const float* __restrict__ tW2, const float* __restrict__ tb2,
                          const float* __restrict__ hW1, const float* __restrict__ hb1,
                          const float* __restrict__ hW2, const float* __restrict__ hb2,
                          unsigned short* __restrict__ WT, uint2* __restrict__ xb,
                          float* __restrict__ qw2m, float* __restrict__ cw2m,
                          float* __restrict__ b2m, float* __restrict__ cT,
                          float* __restrict__ cH, float* __restrict__ rowadd) {
  int b = blockIdx.x, tdx = threadIdx.x;
  if (b < 3072) {
    // WcatT (1536 x 512 bf16, n-major): [ L | quad_W1^T | cubic_W1^T ]
    int idx = b * 256 + tdx;
    int n = idx >> 9;
    int k = idx & 511;
    float v;
    if (n < 512) {
      float th = OMEGA_F * t[0];
      float s1, c1, s2, c2;
      sincosf(th, &s1, &c1);
      sincosf(2.0f * th, &s2, &c2);
      const float* p = fc + ((size_t)n * 512 + k) * 5;
      v = p[0] + p[1] * c1 + p[2] * s1 + p[3] * c2 + p[4] * s2;
    } else if (n < 1024) {
      v = qW1[(size_t)k * 512 + (n - 512)];
    } else {
      v = cW1[(size_t)k * 512 + (n - 1024)];
    }
    WT[idx] = f2bf(v);
  } else if (b < 3076) {
    int bb = b - 3072;
    const float* W = (bb < 2) ? qW2 : cW2;
    float* o = (bb < 2) ? qw2m : cw2m;
    int h = (bb & 1) * 256 + tdx;
    const float4* row = (const float4*)(W + (size_t)h * 512);
    float s = 0.f;
    for (int i = 0; i < 128; ++i) { float4 v = row[i]; s += (v.x + v.y) + (v.z + v.w); }
    o[h] = s * (1.0f / 512.0f);
  } else if (b == 3076) {
    __shared__ float sm[256];
    sm[tdx] = qb2[tdx] + qb2[tdx + 256];
    __syncthreads();
    for (int w = 128; w > 0; w >>= 1) { if (tdx < w) sm[tdx] += sm[tdx + w]; __syncthreads(); }
    if (tdx == 0) b2m[0] = sm[0] * (1.0f / 512.0f);
    __syncthreads();
    sm[tdx] = cb2[tdx] + cb2[tdx + 256];
    __syncthreads();
    for (int w = 128; w > 0; w >>= 1) { if (tdx < w) sm[tdx] += sm[tdx + w]; __syncthreads(); }
    if (tdx == 0) b2m[1] = sm[0] * (1.0f / 512.0f);
  } else if (b < 3077 + 8192) {
    // x -> bf16
    int i = (b - 3077) * 256 + tdx;
    float4 v = x4[i];
    uint2 r;
    r.x = (unsigned)f2bf(v.x) | ((unsigned)f2bf(v.y) << 16);
    r.y = (unsigned)f2bf(v.z) | ((unsigned)f2bf(v.w) << 16);
    xb[i] = r;
  } else {
    // enso tiny MLPs + rowadd zeroing
    int row = (b - 11269) * 256 + tdx;
    rowadd[row] = 0.f;
    float T = x[(size_t)row * 512];
    float H = x[(size_t)row * 512 + 1];
    float fT[5] = {T, H, T * T, T * H, T * T * T};
    float fH[5] = {T, H, T * T, T * H, T * H * H};
    float sT = tb2[0], sH = hb2[0];
#pragma unroll 4
    for (int e = 0; e < 32; ++e) {
      float a1 = tb1[e], a2 = hb1[e];
#pragma unroll
      for (int f = 0; f < 5; ++f) {
        a1 += fT[f] * tW1[f * 32 + e];
        a2 += fH[f] * hW1[f * 32 + e];
      }
      sT += fmaxf(a1, 0.f) * tW2[e];
      sH += fmaxf(a2, 0.f) * hW2[e];
    }
    cT[row] = sT;
    cH[row] = sH;
  }
}

// ---------------------------------------------------------------------------
// GEMM main loop (r3-verified, used by lin_gemm): 128x128 tile, BK=64,
// global_load_lds(16B) staging. LDS: row-major 128x64 elems, 16B chunk
// (row,kc) stored at slot kc^(row&7) (conflict-free).
// ---------------------------------------------------------------------------
#define GEMM_MAINLOOP(A_, Bt_, MB_, NB_)                                          \
  const int tid = threadIdx.x;                                                    \
  const int lane = tid & 63;                                                      \
  const int wave = tid >> 6;                                                      \
  const int wm = wave & 1;                                                        \
  const int wn = wave >> 1;                                                       \
  const int m_base = (MB_);                                                       \
  const int n_base = (NB_);                                                       \
  const int lrow = lane & 15;                                                     \
  const int l7 = lrow & 7;                                                        \
  const int kgrp = lane >> 4;                                                     \
  const int srow = lane >> 3;                                                     \
  const int sk = ((lane & 7) ^ srow) * 8;                                         \
  const unsigned short* gA0 = (A_) + (size_t)(m_base + wave * 8 + srow) * 512 + sk; \
  const unsigned short* gA1 = gA0 + 32 * 512;                                     \
  const unsigned short* gA2 = gA0 + 64 * 512;                                     \
  const unsigned short* gA3 = gA0 + 96 * 512;                                     \
  const unsigned short* gB0 = (Bt_) + (size_t)(n_base + wave * 8 + srow) * 512 + sk;\
  const unsigned short* gB1 = gB0 + 32 * 512;                                     \
  const unsigned short* gB2 = gB0 + 64 * 512;                                     \
  const unsigned short* gB3 = gB0 + 96 * 512;                                     \
  unsigned short* lA0 = As + wave * 512;                                          \
  unsigned short* lA1 = As + (4 + wave) * 512;                                    \
  unsigned short* lA2 = As + (8 + wave) * 512;                                    \
  unsigned short* lA3 = As + (12 + wave) * 512;                                   \
  unsigned short* lB0 = Bs + wave * 512;                                          \
  unsigned short* lB1 = Bs + (4 + wave) * 512;                                    \
  unsigned short* lB2 = Bs + (8 + wave) * 512;                                    \
  unsigned short* lB3 = Bs + (12 + wave) * 512;                                   \
  f32x4 acc[4][4];                                                                \
  _Pragma("unroll") for (int i = 0; i < 4; ++i)                                   \
      _Pragma("unroll") for (int j = 0; j < 4; ++j)                               \
          acc[i][j] = (f32x4){0.f, 0.f, 0.f, 0.f};                                \
  for (int k0 = 0; k0 < 512; k0 += 64) {                                          \
    gload16(gA0, lA0); gload16(gA1, lA1); gload16(gA2, lA2); gload16(gA3, lA3);   \
    gload16(gB0, lB0); gload16(gB1, lB1); gload16(gB2, lB2); gload16(gB3, lB3);   \
    gA0 += 64; gA1 += 64; gA2 += 64; gA3 += 64;                                   \
    gB0 += 64; gB1 += 64; gB2 += 64; gB3 += 64;                                   \
    __syncthreads();                                                              \
    _Pragma("unroll") for (int h = 0; h < 2; ++h) {                               \
      short8 af[4], bfr[4];                                                       \
      const int ks = ((h * 4 + kgrp) ^ l7) * 8;                                   \
      _Pragma("unroll") for (int i = 0; i < 4; ++i)                               \
          af[i] = *(const short8*)(&As[(wm * 64 + i * 16 + lrow) * 64 + ks]);     \
      _Pragma("unroll") for (int j = 0; j < 4; ++j)                               \
          bfr[j] = *(const short8*)(&Bs[(wn * 64 + j * 16 + lrow) * 64 + ks]);    \
      _Pragma("unroll") for (int i = 0; i < 4; ++i)                               \
          _Pragma("unroll") for (int j = 0; j < 4; ++j)                           \
              acc[i][j] = __builtin_amdgcn_mfma_f32_16x16x32_bf16(af[i], bfr[j],  \
                                                                  acc[i][j], 0, 0, 0); \
    }                                                                             \
    __syncthreads();                                                              \
  }

// ---- phase 1: x @ [qW1 | cW1] -> relu.w2m row reduction -> rowadd ----------
// grid (128, 4): block (x,y) computes the 128x256 pair of n-tiles
// [y*256, y*256+255] with ONE k-loop sharing the A-slab in LDS.
__global__ __launch_bounds__(256, 2) void nl_gemm(
    const unsigned short* __restrict__ A,    // 16384 x 512 bf16
    const unsigned short* __restrict__ Bt,   // 1024 x 512 bf16 (WT rows 512..1535)
    const float* __restrict__ qb1, const float* __restrict__ cb1,
    const float* __restrict__ qw2m, const float* __restrict__ cw2m,
    float* __restrict__ rowadd) {
  __shared__ unsigned short As[128 * 64];
  __shared__ unsigned short B0s[128 * 64];
  __shared__ unsigned short B1s[128 * 64];
  const int tid = threadIdx.x;
  const int lane = tid & 63;
  const int wave = tid >> 6;
  const int wm = wave & 1;
  const int wn = wave >> 1;
  const int m_base = blockIdx.x * 128;
  const int n0 = blockIdx.y * 256;          // tile0: cols n0..+127, tile1: +128..+255
  const int lrow = lane & 15;
  const int l7 = lrow & 7;
  const int kgrp = lane >> 4;
  const int srow = lane >> 3;
  const int sk = ((lane & 7) ^ srow) * 8;

  const unsigned short* gA0 = A + (size_t)(m_base + wave * 8 + srow) * 512 + sk;
  const unsigned short* gA1 = gA0 + 32 * 512;
  const unsigned short* gA2 = gA0 + 64 * 512;
  const unsigned short* gA3 = gA0 + 96 * 512;
  const unsigned short* gB00 = Bt + (size_t)(n0 + wave * 8 + srow) * 512 + sk;
  const unsigned short* gB01 = gB00 + 32 * 512;
  const unsigned short* gB02 = gB00 + 64 * 512;
  const unsigned short* gB03 = gB00 + 96 * 512;
  const unsigned short* gB10 = gB00 + 128 * 512;
  const unsigned short* gB11 = gB00 + 160 * 512;
  const unsigned short* gB12 = gB00 + 192 * 512;
  const unsigned short* gB13 = gB00 + 224 * 512;

  unsigned short* lA0 = As + wave * 512;
  unsigned short* lA1 = As + (4 + wave) * 512;
  unsigned short* lA2 = As + (8 + wave) * 512;
  unsigned short* lA3 = As + (12 + wave) * 512;
  unsigned short* lB00 = B0s + wave * 512;
  unsigned short* lB01 = B0s + (4 + wave) * 512;
  unsigned short* lB02 = B0s + (8 + wave) * 512;
  unsigned short* lB03 = B0s + (12 + wave) * 512;
  unsigned short* lB10 = B1s + wave * 512;
  unsigned short* lB11 = B1s + (4 + wave) * 512;
  unsigned short* lB12 = B1s + (8 + wave) * 512;
  unsigned short* lB13 = B1s + (12 + wave) * 512;

  f32x4 acc0[4][4], acc1[4][4];
#pragma unroll
  for (int i = 0; i < 4; ++i)
#pragma unroll
    for (int j = 0; j < 4; ++j) {
      acc0[i][j] = (f32x4){0.f, 0.f, 0.f, 0.f};
      acc1[i][j] = (f32x4){0.f, 0.f, 0.f, 0.f};
    }

  for (int k0 = 0; k0 < 512; k0 += 64) {
    gload16(gA0, lA0); gload16(gA1, lA1); gload16(gA2, lA2); gload16(gA3, lA3);
    gload16(gB00, lB00); gload16(gB01, lB01); gload16(gB02, lB02); gload16(gB03, lB03);
    gload16(gB10, lB10); gload16(gB11, lB11); gload16(gB12, lB12); gload16(gB13, lB13);
    gA0 += 64; gA1 += 64; gA2 += 64; gA3 += 64;
    gB00 += 64; gB01 += 64; gB02 += 64; gB03 += 64;
    gB10 += 64; gB11 += 64; gB12 += 64; gB13 += 64;
    __syncthreads();
#pragma unroll
    for (int h = 0; h < 2; ++h) {
      short8 af[4], b0f[4], b1f[4];
      const int ks = ((h * 4 + kgrp) ^ l7) * 8;
#pragma unroll
      for (int i = 0; i < 4; ++i)
        af[i] = *(const short8*)(&As[(wm * 64 + i * 16 + lrow) * 64 + ks]);
#pragma unroll
      for (int j = 0; j < 4; ++j) {
        b0f[j] = *(const short8*)(&B0s[(wn * 64 + j * 16 + lrow) * 64 + ks]);
        b1f[j] = *(const short8*)(&B1s[(wn * 64 + j * 16 + lrow) * 64 + ks]);
      }
#pragma unroll
      for (int i = 0; i < 4; ++i)
#pragma unroll
        for (int j = 0; j < 4; ++j) {
          acc0[i][j] = __builtin_amdgcn_mfma_f32_16x16x32_bf16(af[i], b0f[j],
                                                               acc0[i][j], 0, 0, 0);
          acc1[i][j] = __builtin_amdgcn_mfma_f32_16x16x32_bf16(af[i], b1f[j],
                                                               acc1[i][j], 0, 0, 0);
        }
    }
    __syncthreads();
  }

  // epilogue: fold both tiles into rs. C/D: col=lane&15, row=(lane>>4)*4+reg.
  // y<2 <=> quad half (pairs never straddle the 512 boundary).
  const bool isq = (n0 < 512);
  const float* b1p = isq ? qb1 : cb1;
  const float* w2m = isq ? qw2m : cw2m;
  const int cb0 = (isq ? n0 : n0 - 512) + wn * 64 + lrow;
  float rs[4][4];
#pragma unroll
  for (int i = 0; i < 4; ++i)
#pragma unroll
    for (int r = 0; r < 4; ++r) rs[i][r] = 0.f;
#pragma unroll
  for (int j = 0; j < 4; ++j) {
    int col0 = cb0 + j * 16;
    float bb0 = b1p[col0], ww0 = w2m[col0];
    float bb1 = b1p[col0 + 128], ww1 = w2m[col0 + 128];
#pragma unroll
    for (int i = 0; i < 4; ++i)
#pragma unroll
      for (int r = 0; r < 4; ++r) {
        rs[i][r] += fmaxf(acc0[i][j][r] + bb0, 0.f) * ww0;
        rs[i][r] += fmaxf(acc1[i][j][r] + bb1, 0.f) * ww1;
      }
  }

  const int rbase = m_base + wm * 64 + kgrp * 4;
#pragma unroll
  for (int i = 0; i < 4; ++i)
#pragma unroll
    for (int r = 0; r < 4; ++r) {
      float v = rs[i][r];
      v += __shfl_xor(v, 1, 64);
      v += __shfl_xor(v, 2, 64);
      v += __shfl_xor(v, 4, 64);
      v += __shfl_xor(v, 8, 64);
      if (lrow == 0) atomicAdd(&rowadd[rbase + i * 16 + r], v);
    }
}

// ---- phase 2: x @ L^T, epilogue folds rowadd + b2 means + enso -> out ------
__global__ __launch_bounds__(256) void lin_gemm(
    const unsigned short* __restrict__ A,    // 16384 x 512 bf16
    const unsigned short* __restrict__ Bt,   // 512 x 512 bf16 (WT rows 0..511)
    const float* __restrict__ rowadd, const float* __restrict__ b2m,
    const float* __restrict__ cT, const float* __restrict__ cH,
    float* __restrict__ out) {
  __shared__ unsigned short As[128 * 64];
  __shared__ unsigned short Bs[128 * 64];
  GEMM_MAINLOOP(A, Bt, blockIdx.x * 128, blockIdx.y * 128)
  const int rbase = m_base + wm * 64 + (lane >> 4) * 4;
  const float b2s = b2m[0] + b2m[1];
  float ra[4][4];
#pragma unroll
  for (int i = 0; i < 4; ++i)
#pragma unroll
    for (int r = 0; r < 4; ++r) ra[i][r] = rowadd[rbase + i * 16 + r] + b2s;
#pragma unroll
  for (int j = 0; j < 4; ++j) {
    int col = n_base + wn * 64 + j * 16 + lrow;
#pragma unroll
    for (int i = 0; i < 4; ++i)
#pragma unroll
      for (int r = 0; r < 4; ++r) {
        int row = rbase + i * 16 + r;
        float v = acc[i][j][r] + ra[i][r];
        if (col == 0) v += cT[row];
        if (col == 1) v += cH[row];
        out[(size_t)row * 512 + col] = v;
      }
  }
}

extern "C" void kernel_launch(void* const* d_in, const int* in_sizes, int n_in,
                              void* d_out, int out_size, void* d_ws, size_t ws_size,
                              hipStream_t stream) {
  const float* x   = (const float*)d_in[0];
  const float* t   = (const float*)d_in[1];
  const float* fc  = (const float*)d_in[2];
  const float* qW1 = (const float*)d_in[3];
  const float* qb1 = (const float*)d_in[4];
  const float* qW2 = (const float*)d_in[5];
  const float* qb2 = (const float*)d_in[6];
  const float* cW1 = (const float*)d_in[7];
  const float* cb1 = (const float*)d_in[8];
  const float* cW2 = (const float*)d_in[9];
  const float* cb2 = (const float*)d_in[10];
  const float* tW1 = (const float*)d_in[11];
  const float* tb1 = (const float*)d_in[12];
  const float* tW2 = (const float*)d_in[13];
  const float* tb2 = (const float*)d_in[14];
  const float* hW1 = (const float*)d_in[15];
  const float* hb1 = (const float*)d_in[16];
  const float* hW2 = (const float*)d_in[17];
  const float* hb2 = (const float*)d_in[18];
  float* out = (float*)d_out;

  // workspace layout (bytes); total ~18.6 MB
  char* ws = (char*)d_ws;
  unsigned short* WT = (unsigned short*)(ws);              // 1536*512*2   = 1,572,864
  unsigned short* xb = (unsigned short*)(ws + 1572864);    // 16384*512*2  = 16,777,216
  float* qw2m   = (float*)(ws + 18350080);                 // 512*4
  float* cw2m   = (float*)(ws + 18352128);                 // 512*4
  float* b2m    = (float*)(ws + 18354176);                 // 2*4 (pad)
  float* cT     = (float*)(ws + 18354432);                 // 16384*4
  float* cH     = (float*)(ws + 18419968);                 // 16384*4
  float* rowadd = (float*)(ws + 18485504);                 // 16384*4 -> ends 18,551,040

  prep_conv<<<11333, 256, 0, stream>>>(fc, qW1, cW1, t, qW2, cW2, qb2, cb2,
                                       (const float4*)x, x,
                                       tW1, tb1, tW2, tb2, hW1, hb1, hW2, hb2,
                                       WT, (uint2*)xb, qw2m, cw2m, b2m, cT, cH,
                                       rowadd);
  nl_gemm<<<dim3(128, 4), 256, 0, stream>>>(xb, WT + (size_t)512 * 512,
                                            qb1, cb1, qw2m, cw2m, rowadd);
  lin_gemm<<<dim3(128, 4), 256, 0, stream>>>(xb, WT, rowadd, b2m, cT, cH, out);
}